// Round 1
// baseline (151.961 us; speedup 1.0000x reference)
//
#include <hip/hip_runtime.h>

// Pairwise cosine similarity: C[i][j] = <x_i/||x_i||, y_j/||y_j||>
// x,y: [8192][512] f32.  Out: [8192][8192] f32.
// Stage 1: row-normalize -> bf16 in d_ws (xn 8MB + yn 8MB).
// Stage 2: bf16 MFMA GEMM C = Xn * Yn^T (NT), m97 structure:
//   128x128 tile, BK=32, 4 waves (2x2 of 64x64), 16x16x32 MFMA,
//   global_load_lds width=16 staging, XCD-aware block swizzle.

typedef __attribute__((ext_vector_type(8))) short bf16x8;
typedef __attribute__((ext_vector_type(4))) float f32x4;
typedef __attribute__((ext_vector_type(8))) unsigned short ushort8;

#define M_DIM 8192
#define N_DIM 8192
#define K_DIM 512

static __device__ __forceinline__ unsigned short f32_to_bf16(float f) {
  unsigned int u = __float_as_uint(f);
  u = (u + 0x7FFFu + ((u >> 16) & 1u)) >> 16;  // round-to-nearest-even
  return (unsigned short)u;
}

// One wave per row (512 f32 = 64 lanes x 8). Block 256 = 4 rows.
__global__ __launch_bounds__(256) void normalize_rows(
    const float* __restrict__ in, unsigned short* __restrict__ out) {
  const int wid = threadIdx.x >> 6;
  const int lane = threadIdx.x & 63;
  const int row = (blockIdx.x << 2) + wid;
  const float4* r = (const float4*)(in + (size_t)row * K_DIM);
  float4 v0 = r[lane * 2];
  float4 v1 = r[lane * 2 + 1];
  float ss = v0.x * v0.x + v0.y * v0.y + v0.z * v0.z + v0.w * v0.w +
             v1.x * v1.x + v1.y * v1.y + v1.z * v1.z + v1.w * v1.w;
#pragma unroll
  for (int off = 32; off; off >>= 1) ss += __shfl_xor(ss, off, 64);
  const float s = 1.0f / fmaxf(sqrtf(ss), 1e-8f);
  const float f[8] = {v0.x, v0.y, v0.z, v0.w, v1.x, v1.y, v1.z, v1.w};
  union { ushort8 v; unsigned short u[8]; } o;
#pragma unroll
  for (int i = 0; i < 8; ++i) o.u[i] = f32_to_bf16(f[i] * s);
  *(ushort8*)(out + (size_t)row * K_DIM + lane * 8) = o.v;
}

static __device__ __forceinline__ void gload_lds16(const unsigned short* g,
                                                   unsigned short* l) {
  // 16B per lane, LDS dest = wave-uniform base + lane*16
  __builtin_amdgcn_global_load_lds(
      (const __attribute__((address_space(1))) unsigned int*)g,
      (__attribute__((address_space(3))) unsigned int*)l, 16, 0, 0);
}

__global__ __launch_bounds__(256) void cosgemm(
    const unsigned short* __restrict__ A,   // xn bf16 [8192][512]
    const unsigned short* __restrict__ B,   // yn bf16 [8192][512]
    float* __restrict__ C) {                // [8192][8192]
  __shared__ __align__(16) unsigned short Al[128 * 32];
  __shared__ __align__(16) unsigned short Bl[128 * 32];

  const int tid = threadIdx.x;
  const int lane = tid & 63;
  const int wid = tid >> 6;

  // XCD-aware swizzle: blocks with same (bid%8) land on the same XCD;
  // give each XCD a contiguous chunk of tile space (4096 % 8 == 0).
  const int bid = blockIdx.x;
  const int cpx = gridDim.x >> 3;  // 512
  const int swz = (bid & 7) * cpx + (bid >> 3);
  const int bx = swz & 63;         // col tile
  const int by = swz >> 6;         // row tile
  const int row0 = by << 7;
  const int col0 = bx << 7;

  // Staging decomposition: thread t stages 16B = 8 bf16 at flat tile elems
  // t*8 (inst 0: rows 0..63) and 2048+t*8 (inst 1: rows 64..127).
  const int srow = tid >> 2;            // 0..63
  const int scol = (tid & 3) << 3;      // 0,8,16,24
  const unsigned short* ga = A + (size_t)(row0 + srow) * K_DIM + scol;
  const unsigned short* gb = B + (size_t)(col0 + srow) * K_DIM + scol;
  unsigned short* la0 = &Al[wid << 9];
  unsigned short* la1 = &Al[2048 + (wid << 9)];
  unsigned short* lb0 = &Bl[wid << 9];
  unsigned short* lb1 = &Bl[2048 + (wid << 9)];

  const int wr = (wid >> 1) << 6;   // wave row offset in tile
  const int wc = (wid & 1) << 6;    // wave col offset in tile
  const int lr = lane & 15;
  const int lk = (lane >> 4) << 3;

  f32x4 acc[4][4] = {};

  for (int kt = 0; kt < K_DIM; kt += 32) {
    __syncthreads();  // previous tile's compute done before overwrite
    gload_lds16(ga + kt, la0);
    gload_lds16(ga + (size_t)64 * K_DIM + kt, la1);
    gload_lds16(gb + kt, lb0);
    gload_lds16(gb + (size_t)64 * K_DIM + kt, lb1);
    __syncthreads();  // drains vmcnt(0): staged data visible

    bf16x8 af[4], bb[4];
#pragma unroll
    for (int m = 0; m < 4; ++m)
      af[m] = *(const bf16x8*)&Al[(wr + m * 16 + lr) * 32 + lk];
#pragma unroll
    for (int n = 0; n < 4; ++n)
      bb[n] = *(const bf16x8*)&Bl[(wc + n * 16 + lr) * 32 + lk];

#pragma unroll
    for (int m = 0; m < 4; ++m)
#pragma unroll
      for (int n = 0; n < 4; ++n)
        acc[m][n] = __builtin_amdgcn_mfma_f32_16x16x32_bf16(af[m], bb[n],
                                                            acc[m][n], 0, 0, 0);
  }

  // C/D layout (m89, verified): col = lane&15, row = (lane>>4)*4 + reg
  const int crow = row0 + wr + ((lane >> 4) << 2);
  const int ccol = col0 + wc + lr;
#pragma unroll
  for (int m = 0; m < 4; ++m)
#pragma unroll
    for (int n = 0; n < 4; ++n)
#pragma unroll
      for (int i = 0; i < 4; ++i)
        C[(size_t)(crow + m * 16 + i) * N_DIM + (ccol + n * 16)] = acc[m][n][i];
}

extern "C" void kernel_launch(void* const* d_in, const int* in_sizes, int n_in,
                              void* d_out, int out_size, void* d_ws, size_t ws_size,
                              hipStream_t stream) {
  const float* x = (const float*)d_in[0];
  const float* y = (const float*)d_in[1];
  float* out = (float*)d_out;
  unsigned short* xn = (unsigned short*)d_ws;                    // 8 MB
  unsigned short* yn = xn + (size_t)M_DIM * K_DIM;               // 8 MB

  normalize_rows<<<M_DIM / 4, 256, 0, stream>>>(x, xn);
  normalize_rows<<<N_DIM / 4, 256, 0, stream>>>(y, yn);
  cosgemm<<<(M_DIM / 128) * (N_DIM / 128), 256, 0, stream>>>(xn, yn, out);
}

// Round 2
// 144.089 us; speedup vs baseline: 1.0546x; 1.0546x over previous
//
#include <hip/hip_runtime.h>

// Pairwise cosine similarity: C[i][j] = <x_i/||x_i||, y_j/||y_j||>
// x,y: [8192][512] f32.  Out: [8192][8192] f32.
// Stage 1: row-normalize -> bf16 in d_ws (xn 8MB + yn 8MB).
// Stage 2: bf16 MFMA GEMM C = Xn * Yn^T (NT):
//   128x128 tile, BK=64, 4 waves (2x2 of 64x64), 16x16x32 MFMA,
//   global_load_lds width=16 staging with row-local XOR swizzle (T2,
//   both-sides: pre-swizzled global source + swizzled ds_read),
//   coalesced 256B epilogue stores via per-wave LDS transpose strip
//   (kills the 266MB read-modify-write fetch seen in R1),
//   XCD-aware block swizzle (T1).

typedef __attribute__((ext_vector_type(8))) short bf16x8;
typedef __attribute__((ext_vector_type(4))) float f32x4;
typedef __attribute__((ext_vector_type(8))) unsigned short ushort8;

#define M_DIM 8192
#define N_DIM 8192
#define K_DIM 512
#define BK 64

static __device__ __forceinline__ unsigned short f32_to_bf16(float f) {
  unsigned int u = __float_as_uint(f);
  u = (u + 0x7FFFu + ((u >> 16) & 1u)) >> 16;  // round-to-nearest-even
  return (unsigned short)u;
}

// One wave per row (512 f32 = 64 lanes x 8). Block 256 = 4 rows.
__global__ __launch_bounds__(256) void normalize_rows(
    const float* __restrict__ in, unsigned short* __restrict__ out) {
  const int wid = threadIdx.x >> 6;
  const int lane = threadIdx.x & 63;
  const int row = (blockIdx.x << 2) + wid;
  const float4* r = (const float4*)(in + (size_t)row * K_DIM);
  float4 v0 = r[lane * 2];
  float4 v1 = r[lane * 2 + 1];
  float ss = v0.x * v0.x + v0.y * v0.y + v0.z * v0.z + v0.w * v0.w +
             v1.x * v1.x + v1.y * v1.y + v1.z * v1.z + v1.w * v1.w;
#pragma unroll
  for (int off = 32; off; off >>= 1) ss += __shfl_xor(ss, off, 64);
  const float s = 1.0f / fmaxf(sqrtf(ss), 1e-8f);
  const float f[8] = {v0.x, v0.y, v0.z, v0.w, v1.x, v1.y, v1.z, v1.w};
  union { ushort8 v; unsigned short u[8]; } o;
#pragma unroll
  for (int i = 0; i < 8; ++i) o.u[i] = f32_to_bf16(f[i] * s);
  *(ushort8*)(out + (size_t)row * K_DIM + lane * 8) = o.v;
}

static __device__ __forceinline__ void gload_lds16(const unsigned short* g,
                                                   unsigned short* l) {
  // 16B per lane, LDS dest = wave-uniform base + lane*16 (linear)
  __builtin_amdgcn_global_load_lds(
      (const __attribute__((address_space(1))) unsigned int*)g,
      (__attribute__((address_space(3))) unsigned int*)l, 16, 0, 0);
}

__global__ __launch_bounds__(256) void cosgemm(
    const unsigned short* __restrict__ A,   // xn bf16 [8192][512]
    const unsigned short* __restrict__ B,   // yn bf16 [8192][512]
    float* __restrict__ C) {                // [8192][8192]
  // Al/Bl: [128][BK=64] bf16 (128B rows), 16KB each. Epilogue reuses all
  // 32KB as four 8KB per-wave f32 transpose strips.
  __shared__ __align__(16) unsigned char smem[32768];
  unsigned short* Al = (unsigned short*)smem;
  unsigned short* Bl = (unsigned short*)(smem + 16384);

  const int tid = threadIdx.x;
  const int lane = tid & 63;
  const int wid = tid >> 6;

  // XCD-aware swizzle (4096 % 8 == 0 -> bijective)
  const int bid = blockIdx.x;
  const int cpx = gridDim.x >> 3;
  const int swz = (bid & 7) * cpx + (bid >> 3);
  const int bx = swz & 63;         // col tile
  const int by = swz >> 6;         // row tile
  const int row0 = by << 7;
  const int col0 = bx << 7;

  // ---- staging geometry (per wave, 4 chunk-calls of 4KB each) ----
  // chunk c: rows c*32 + wid*8 + (lane>>3); slot (16B unit) = lane&7.
  // LDS dest linear; global source k pre-swizzled: slot ^= (row&7).
  const int r0s = (wid << 3) + (lane >> 3);       // row within 32-row chunk
  const int sslot = (lane & 7) ^ (r0s & 7);       // pre-swizzled 16B slot
  const unsigned short* ga[4];
  const unsigned short* gb[4];
#pragma unroll
  for (int c = 0; c < 4; ++c) {
    const int r = c * 32 + r0s;
    ga[c] = A + (size_t)(row0 + r) * K_DIM + sslot * 8;
    gb[c] = B + (size_t)(col0 + r) * K_DIM + sslot * 8;
  }
  unsigned short* const lbase = (unsigned short*)((wid << 10));  // byte off

  const int wr = (wid >> 1) << 6;   // wave row offset in tile
  const int wc = (wid & 1) << 6;    // wave col offset in tile
  const int lr = lane & 15;
  const int hk = lane >> 4;         // 0..3 (k sub-slot)

  // ds_read byte offsets (swizzled): row*128 + ((half*4 + hk) ^ (row&7))*16
  int aoff[2][4], boff[2][4];
#pragma unroll
  for (int half = 0; half < 2; ++half)
#pragma unroll
    for (int m = 0; m < 4; ++m) {
      const int ra = wr + m * 16 + lr;
      aoff[half][m] = ra * 128 + (((half * 4 + hk) ^ (ra & 7)) << 4);
      const int rb = wc + m * 16 + lr;
      boff[half][m] = rb * 128 + (((half * 4 + hk) ^ (rb & 7)) << 4);
    }

  f32x4 acc[4][4] = {};

  for (int kt = 0; kt < K_DIM; kt += BK) {
    __syncthreads();  // previous step's compute done before overwrite
#pragma unroll
    for (int c = 0; c < 4; ++c) {
      gload_lds16(ga[c] + kt, (unsigned short*)((unsigned char*)Al +
                                                (c << 12) + (size_t)lbase));
      gload_lds16(gb[c] + kt, (unsigned short*)((unsigned char*)Bl +
                                                (c << 12) + (size_t)lbase));
    }
    __syncthreads();  // drains vmcnt(0): staged data visible

    bf16x8 af[2][4], bb[2][4];
#pragma unroll
    for (int half = 0; half < 2; ++half)
#pragma unroll
      for (int m = 0; m < 4; ++m) {
        af[half][m] = *(const bf16x8*)((const unsigned char*)Al + aoff[half][m]);
        bb[half][m] = *(const bf16x8*)((const unsigned char*)Bl + boff[half][m]);
      }

#pragma unroll
    for (int m = 0; m < 4; ++m)
#pragma unroll
      for (int n = 0; n < 4; ++n) {
        acc[m][n] = __builtin_amdgcn_mfma_f32_16x16x32_bf16(af[0][m], bb[0][n],
                                                            acc[m][n], 0, 0, 0);
        acc[m][n] = __builtin_amdgcn_mfma_f32_16x16x32_bf16(af[1][m], bb[1][n],
                                                            acc[m][n], 0, 0, 0);
      }
  }

  // ---- coalesced epilogue: per-wave [16][68]-padded f32 strip in LDS ----
  __syncthreads();  // everyone done reading Al/Bl
  float* Sl = (float*)(smem + (wid << 13));  // 8KB per wave (uses 4352B)
#pragma unroll
  for (int m = 0; m < 4; ++m) {
    // scatter MFMA fragments: row (hk*4+i), col (n*16+lr)
#pragma unroll
    for (int n = 0; n < 4; ++n)
#pragma unroll
      for (int i = 0; i < 4; ++i)
        Sl[(hk * 4 + i) * 68 + n * 16 + lr] = acc[m][n][i];
    // read back row-major, store 256B-contiguous per 16-lane group
#pragma unroll
    for (int j = 0; j < 4; ++j) {
      f32x4 v = *(const f32x4*)&Sl[(j * 4 + hk) * 68 + lr * 4];
      *(f32x4*)&C[(size_t)(row0 + wr + m * 16 + j * 4 + hk) * N_DIM +
                  (col0 + wc + lr * 4)] = v;
    }
    // wave-private strip; compiler orders ds ops of next m via lgkmcnt
  }
}

extern "C" void kernel_launch(void* const* d_in, const int* in_sizes, int n_in,
                              void* d_out, int out_size, void* d_ws, size_t ws_size,
                              hipStream_t stream) {
  const float* x = (const float*)d_in[0];
  const float* y = (const float*)d_in[1];
  float* out = (float*)d_out;
  unsigned short* xn = (unsigned short*)d_ws;                    // 8 MB
  unsigned short* yn = xn + (size_t)M_DIM * K_DIM;               // 8 MB

  normalize_rows<<<M_DIM / 4, 256, 0, stream>>>(x, xn);
  normalize_rows<<<N_DIM / 4, 256, 0, stream>>>(y, yn);
  cosgemm<<<(M_DIM / 128) * (N_DIM / 128), 256, 0, stream>>>(xn, yn, out);
}

// Round 3
// 132.510 us; speedup vs baseline: 1.1468x; 1.0874x over previous
//
#include <hip/hip_runtime.h>

// Pairwise cosine similarity: C[i][j] = <x_i/||x_i||, y_j/||y_j||>
// x,y: [8192][512] f32.  Out: [8192][8192] f32.
// Stage 1: row-normalize -> bf16 in d_ws (xn 8MB + yn 8MB).
// Stage 2: bf16 MFMA GEMM C = Xn * Yn^T (NT):
//   128x128 tile, BK=64, 4 waves (2x2 of 64x64), 16x16x32 MFMA,
//   global_load_lds width=16 staging with row-local XOR swizzle (T2),
//   coalesced 256B epilogue via per-wave LDS transpose strip,
//   NONTEMPORAL C stores (R2 showed TCC write-allocate fetches every
//   output line from HBM: FETCH_SIZE == output size; nt = no-allocate),
//   XCD-aware block swizzle (T1).

typedef __attribute__((ext_vector_type(8))) short bf16x8;
typedef __attribute__((ext_vector_type(4))) float f32x4;
typedef __attribute__((ext_vector_type(8))) unsigned short ushort8;

#define M_DIM 8192
#define N_DIM 8192
#define K_DIM 512
#define BK 64

static __device__ __forceinline__ unsigned short f32_to_bf16(float f) {
  unsigned int u = __float_as_uint(f);
  u = (u + 0x7FFFu + ((u >> 16) & 1u)) >> 16;  // round-to-nearest-even
  return (unsigned short)u;
}

// One wave per row (512 f32 = 64 lanes x 8). Block 256 = 4 rows.
__global__ __launch_bounds__(256) void normalize_rows(
    const float* __restrict__ in, unsigned short* __restrict__ out) {
  const int wid = threadIdx.x >> 6;
  const int lane = threadIdx.x & 63;
  const int row = (blockIdx.x << 2) + wid;
  const float4* r = (const float4*)(in + (size_t)row * K_DIM);
  float4 v0 = r[lane * 2];
  float4 v1 = r[lane * 2 + 1];
  float ss = v0.x * v0.x + v0.y * v0.y + v0.z * v0.z + v0.w * v0.w +
             v1.x * v1.x + v1.y * v1.y + v1.z * v1.z + v1.w * v1.w;
#pragma unroll
  for (int off = 32; off; off >>= 1) ss += __shfl_xor(ss, off, 64);
  const float s = 1.0f / fmaxf(sqrtf(ss), 1e-8f);
  const float f[8] = {v0.x, v0.y, v0.z, v0.w, v1.x, v1.y, v1.z, v1.w};
  union { ushort8 v; unsigned short u[8]; } o;
#pragma unroll
  for (int i = 0; i < 8; ++i) o.u[i] = f32_to_bf16(f[i] * s);
  *(ushort8*)(out + (size_t)row * K_DIM + lane * 8) = o.v;
}

static __device__ __forceinline__ void gload_lds16(const unsigned short* g,
                                                   unsigned short* l) {
  // 16B per lane, LDS dest = wave-uniform base + lane*16 (linear)
  __builtin_amdgcn_global_load_lds(
      (const __attribute__((address_space(1))) unsigned int*)g,
      (__attribute__((address_space(3))) unsigned int*)l, 16, 0, 0);
}

__global__ __launch_bounds__(256) void cosgemm(
    const unsigned short* __restrict__ A,   // xn bf16 [8192][512]
    const unsigned short* __restrict__ B,   // yn bf16 [8192][512]
    float* __restrict__ C) {                // [8192][8192]
  // Al/Bl: [128][BK=64] bf16 (128B rows), 16KB each. Epilogue reuses all
  // 32KB as four 8KB per-wave f32 transpose strips.
  __shared__ __align__(16) unsigned char smem[32768];
  unsigned short* Al = (unsigned short*)smem;
  unsigned short* Bl = (unsigned short*)(smem + 16384);

  const int tid = threadIdx.x;
  const int lane = tid & 63;
  const int wid = tid >> 6;

  // XCD-aware swizzle (4096 % 8 == 0 -> bijective)
  const int bid = blockIdx.x;
  const int cpx = gridDim.x >> 3;
  const int swz = (bid & 7) * cpx + (bid >> 3);
  const int bx = swz & 63;         // col tile
  const int by = swz >> 6;         // row tile
  const int row0 = by << 7;
  const int col0 = bx << 7;

  // ---- staging geometry (per wave, 4 chunk-calls of 4KB each) ----
  // chunk c: rows c*32 + wid*8 + (lane>>3); slot (16B unit) = lane&7.
  // LDS dest linear; global source k pre-swizzled: slot ^= (row&7).
  const int r0s = (wid << 3) + (lane >> 3);       // row within 32-row chunk
  const int sslot = (lane & 7) ^ (r0s & 7);       // pre-swizzled 16B slot
  const unsigned short* ga[4];
  const unsigned short* gb[4];
#pragma unroll
  for (int c = 0; c < 4; ++c) {
    const int r = c * 32 + r0s;
    ga[c] = A + (size_t)(row0 + r) * K_DIM + sslot * 8;
    gb[c] = B + (size_t)(col0 + r) * K_DIM + sslot * 8;
  }
  unsigned short* const lbase = (unsigned short*)((wid << 10));  // byte off

  const int wr = (wid >> 1) << 6;   // wave row offset in tile
  const int wc = (wid & 1) << 6;    // wave col offset in tile
  const int lr = lane & 15;
  const int hk = lane >> 4;         // 0..3 (k sub-slot)

  // ds_read byte offsets (swizzled): row*128 + ((half*4 + hk) ^ (row&7))*16
  int aoff[2][4], boff[2][4];
#pragma unroll
  for (int half = 0; half < 2; ++half)
#pragma unroll
    for (int m = 0; m < 4; ++m) {
      const int ra = wr + m * 16 + lr;
      aoff[half][m] = ra * 128 + (((half * 4 + hk) ^ (ra & 7)) << 4);
      const int rb = wc + m * 16 + lr;
      boff[half][m] = rb * 128 + (((half * 4 + hk) ^ (rb & 7)) << 4);
    }

  f32x4 acc[4][4] = {};

  for (int kt = 0; kt < K_DIM; kt += BK) {
    __syncthreads();  // previous step's compute done before overwrite
#pragma unroll
    for (int c = 0; c < 4; ++c) {
      gload_lds16(ga[c] + kt, (unsigned short*)((unsigned char*)Al +
                                                (c << 12) + (size_t)lbase));
      gload_lds16(gb[c] + kt, (unsigned short*)((unsigned char*)Bl +
                                                (c << 12) + (size_t)lbase));
    }
    __syncthreads();  // drains vmcnt(0): staged data visible

    bf16x8 af[2][4], bb[2][4];
#pragma unroll
    for (int half = 0; half < 2; ++half)
#pragma unroll
      for (int m = 0; m < 4; ++m) {
        af[half][m] = *(const bf16x8*)((const unsigned char*)Al + aoff[half][m]);
        bb[half][m] = *(const bf16x8*)((const unsigned char*)Bl + boff[half][m]);
      }

#pragma unroll
    for (int m = 0; m < 4; ++m)
#pragma unroll
      for (int n = 0; n < 4; ++n) {
        acc[m][n] = __builtin_amdgcn_mfma_f32_16x16x32_bf16(af[0][m], bb[0][n],
                                                            acc[m][n], 0, 0, 0);
        acc[m][n] = __builtin_amdgcn_mfma_f32_16x16x32_bf16(af[1][m], bb[1][n],
                                                            acc[m][n], 0, 0, 0);
      }
  }

  // ---- coalesced epilogue: per-wave [16][68]-padded f32 strip in LDS ----
  __syncthreads();  // everyone done reading Al/Bl
  float* Sl = (float*)(smem + (wid << 13));  // 8KB per wave (uses 4352B)
#pragma unroll
  for (int m = 0; m < 4; ++m) {
    // scatter MFMA fragments: row (hk*4+i), col (n*16+lr)
#pragma unroll
    for (int n = 0; n < 4; ++n)
#pragma unroll
      for (int i = 0; i < 4; ++i)
        Sl[(hk * 4 + i) * 68 + n * 16 + lr] = acc[m][n][i];
    // read back row-major, store 256B-contiguous per 16-lane group
#pragma unroll
    for (int j = 0; j < 4; ++j) {
      f32x4 v = *(const f32x4*)&Sl[(j * 4 + hk) * 68 + lr * 4];
      // nontemporal: no write-allocate -> kills the 266MB RMW line fetch
      __builtin_nontemporal_store(
          v, (f32x4*)&C[(size_t)(row0 + wr + m * 16 + j * 4 + hk) * N_DIM +
                        (col0 + wc + lr * 4)]);
    }
    // wave-private strip; compiler orders ds ops of next m via lgkmcnt
  }
}

extern "C" void kernel_launch(void* const* d_in, const int* in_sizes, int n_in,
                              void* d_out, int out_size, void* d_ws, size_t ws_size,
                              hipStream_t stream) {
  const float* x = (const float*)d_in[0];
  const float* y = (const float*)d_in[1];
  float* out = (float*)d_out;
  unsigned short* xn = (unsigned short*)d_ws;                    // 8 MB
  unsigned short* yn = xn + (size_t)M_DIM * K_DIM;               // 8 MB

  normalize_rows<<<M_DIM / 4, 256, 0, stream>>>(x, xn);
  normalize_rows<<<N_DIM / 4, 256, 0, stream>>>(y, yn);
  cosgemm<<<(M_DIM / 128) * (N_DIM / 128), 256, 0, stream>>>(xn, yn, out);
}

// Round 4
// 111.344 us; speedup vs baseline: 1.3648x; 1.1901x over previous
//
#include <hip/hip_runtime.h>

// Pairwise cosine similarity: C[i][j] = <x_i/||x_i||, y_j/||y_j||>
// x,y: [8192][512] f32.  Out: [8192][8192] f32.
// Stage 1: row-normalize -> bf16 in d_ws (xn 8MB + yn 8MB).
// Stage 2: 256x256-tile 8-phase bf16 MFMA GEMM (T1+T2+T3+T4+T5):
//   BK=64, 8 waves (2Mx4N), per-wave 128x64 output, 128KB dbuf LDS,
//   counted vmcnt(4) (never 0 mid-loop), per-phase half-tile prefetch,
//   XOR-swizzled LDS (linear gload_lds dest + inverse-swizzled global src),
//   setprio around MFMA clusters, XCD 4-row-band ordering for L2 reuse,
//   LDS-transpose nontemporal epilogue (256B-contiguous row stores).
//
// Schedule (iter i computes K-tiles t=2i,u=2i+1; 4 half-tiles/tile:
// Ah0,Ah1,Bh0,Bh1; 2 gload_lds instr per half-tile per wave):
//  P1 rdA(t,0-3)+rdB(t,0-1) stage u.Ah0 | P2 rdB(t,2-3) stage u.Ah1
//  P3 rdA(t,4-7) stage (t+2).Bh0       | P4 stage (t+2).Bh1, vmcnt(4)
//  P5 rdA(u,0-3)+rdB(u,0-1) st (t+2).Ah0 | P6 rdB(u,2-3) st (t+2).Ah1
//  P7 rdA(u,4-7) st (t+3).Bh0          | P8 st (t+3).Bh1, vmcnt(4)
// Every stage targets a region whose last reader finished >=1 barrier
// earlier; every consumed tile is vmcnt(4)+barrier-confirmed.

typedef __attribute__((ext_vector_type(8))) short bf16x8;
typedef __attribute__((ext_vector_type(4))) float f32x4;
typedef __attribute__((ext_vector_type(8))) unsigned short ushort8;

#define M_DIM 8192
#define N_DIM 8192
#define K_DIM 512

static __device__ __forceinline__ unsigned short f32_to_bf16(float f) {
  unsigned int u = __float_as_uint(f);
  u = (u + 0x7FFFu + ((u >> 16) & 1u)) >> 16;  // round-to-nearest-even
  return (unsigned short)u;
}

__global__ __launch_bounds__(256) void normalize_rows(
    const float* __restrict__ in, unsigned short* __restrict__ out) {
  const int wid = threadIdx.x >> 6;
  const int lane = threadIdx.x & 63;
  const int row = (blockIdx.x << 2) + wid;
  const float4* r = (const float4*)(in + (size_t)row * K_DIM);
  float4 v0 = r[lane * 2];
  float4 v1 = r[lane * 2 + 1];
  float ss = v0.x * v0.x + v0.y * v0.y + v0.z * v0.z + v0.w * v0.w +
             v1.x * v1.x + v1.y * v1.y + v1.z * v1.z + v1.w * v1.w;
#pragma unroll
  for (int off = 32; off; off >>= 1) ss += __shfl_xor(ss, off, 64);
  const float s = 1.0f / fmaxf(sqrtf(ss), 1e-8f);
  const float f[8] = {v0.x, v0.y, v0.z, v0.w, v1.x, v1.y, v1.z, v1.w};
  union { ushort8 v; unsigned short u[8]; } o;
#pragma unroll
  for (int i = 0; i < 8; ++i) o.u[i] = f32_to_bf16(f[i] * s);
  *(ushort8*)(out + (size_t)row * K_DIM + lane * 8) = o.v;
}

static __device__ __forceinline__ void gl16(const unsigned short* g, char* l) {
  __builtin_amdgcn_global_load_lds(
      (const __attribute__((address_space(1))) unsigned int*)g,
      (__attribute__((address_space(3))) unsigned int*)l, 16, 0, 0);
}

#define BAR() __builtin_amdgcn_s_barrier()
#define SBAR() __builtin_amdgcn_sched_barrier(0)
#define LGKM0() do { asm volatile("s_waitcnt lgkmcnt(0)" ::: "memory"); \
                     __builtin_amdgcn_sched_barrier(0); } while (0)
#define VMCNT(n) do { asm volatile("s_waitcnt vmcnt(" #n ")" ::: "memory"); \
                      __builtin_amdgcn_sched_barrier(0); } while (0)

__global__ __launch_bounds__(512, 2) void cosgemm(
    const unsigned short* __restrict__ A,   // xn bf16 [8192][512]
    const unsigned short* __restrict__ B,   // yn bf16 [8192][512]
    float* __restrict__ C) {                // [8192][8192]
  extern __shared__ char smem[];  // 128KB: buf[2] x {A 32K, B 32K}, halves 16K

  const int tid = threadIdx.x;
  const int lane = tid & 63;
  const int wid = tid >> 6;
  const int wm = wid >> 2;        // 0..1  (M half)
  const int wn = wid & 3;         // 0..3  (N quarter)
  const int lr16 = lane & 15;
  const int hq = lane >> 4;       // 0..3
  const int x7 = lane & 7;

  // XCD band ordering: xcd = bid&7; within XCD walk a 4-row band
  // column-major so each B-panel is reused by 4 consecutive blocks and
  // the 4 A-panels (1MB) stay L2-resident.
  const int bid = blockIdx.x;
  const int L = bid >> 3;                   // 0..127
  const int by = ((bid & 7) << 2) + (L & 3);
  const int bx = L >> 2;
  const int row0 = by << 8;
  const int col0 = bx << 8;

  // ---- staging bases: thread covers (row = c*64 + tid/8, 16B slot tid&7),
  // global k pre-swizzled (slot ^ row&7) so linear LDS dest + swizzled
  // ds_read form the same involution (rule #21).
  const int rl = tid >> 3;
  const int sl = (tid & 7) ^ (rl & 7);
  const unsigned short* qA[2], * qB[2];
  qA[0] = A + (size_t)(row0 + rl) * K_DIM + sl * 8;
  qA[1] = A + (size_t)(row0 + 64 + rl) * K_DIM + sl * 8;
  qB[0] = B + (size_t)(col0 + rl) * K_DIM + sl * 8;
  qB[1] = B + (size_t)(col0 + 64 + rl) * K_DIM + sl * 8;

  auto stage = [&](int op, int half, int t) {  // one half-tile = 2 gload_lds
    const unsigned short* g0 = (op ? qB[0] : qA[0]) + half * 65536 + t * 64;
    const unsigned short* g1 = (op ? qB[1] : qA[1]) + half * 65536 + t * 64;
    char* l = smem + ((t & 1) << 16) + (op << 15) + (half << 14) + (wid << 10);
    gl16(g0, l);
    gl16(g1, l + 8192);
  };

  bf16x8 af[4][2], bf[4][2];
  f32x4 acc[8][4] = {};

  auto ldA = [&](int t, int fmBase) {   // 8 x ds_read_b128
#pragma unroll
    for (int j = 0; j < 4; ++j) {
      const char* base = smem + ((t & 1) << 16) + (wm << 14) +
                         ((fmBase + j) * 16 + lr16) * 128;
#pragma unroll
      for (int kk = 0; kk < 2; ++kk)
        af[j][kk] = *(const bf16x8*)(base + ((((kk << 2) | hq) ^ x7) << 4));
    }
  };
  auto ldB = [&](int t, int fnBase) {   // 4 x ds_read_b128
#pragma unroll
    for (int j = 0; j < 2; ++j) {
      const char* base = smem + ((t & 1) << 16) + 32768 + ((wn >> 1) << 14) +
                         (((wn & 1) << 6) + (fnBase + j) * 16 + lr16) * 128;
#pragma unroll
      for (int kk = 0; kk < 2; ++kk)
        bf[fnBase + j][kk] =
            *(const bf16x8*)(base + ((((kk << 2) | hq) ^ x7) << 4));
    }
  };
  auto mm = [&](int fmBase, int fnBase) {  // 16 MFMA
    __builtin_amdgcn_s_setprio(1);
#pragma unroll
    for (int m = 0; m < 4; ++m)
#pragma unroll
      for (int n = 0; n < 2; ++n)
#pragma unroll
        for (int kk = 0; kk < 2; ++kk)
          acc[fmBase + m][fnBase + n] = __builtin_amdgcn_mfma_f32_16x16x32_bf16(
              af[m][kk], bf[fnBase + n][kk], acc[fmBase + m][fnBase + n], 0, 0, 0);
    __builtin_amdgcn_s_setprio(0);
  };

  // ---- prologue: tile0 complete + tile1 B-halves; confirm tile0 landed
  stage(0, 0, 0); stage(0, 1, 0); stage(1, 0, 0); stage(1, 1, 0);
  stage(1, 0, 1); stage(1, 1, 1);
  VMCNT(4);        // 12 issued, <=4 outstanding -> tile0's 8 landed
  BAR(); SBAR();

#pragma unroll
  for (int i = 0; i < 4; ++i) {
    const int t = 2 * i, u = 2 * i + 1;
    // P1
    ldA(t, 0); ldB(t, 0); stage(0, 0, u);
    BAR(); LGKM0(); mm(0, 0); BAR();
    // P2
    ldB(t, 2); stage(0, 1, u);
    BAR(); LGKM0(); mm(0, 2); BAR();
    // P3
    ldA(t, 4); if (i < 3) stage(1, 0, t + 2);
    BAR(); LGKM0(); mm(4, 0); BAR();
    // P4  (confirm tile u fully landed before P5 reads it)
    if (i < 3) stage(1, 1, t + 2);
    BAR(); LGKM0(); mm(4, 2);
    if (i < 3) { VMCNT(4); } else { VMCNT(0); }
    BAR(); SBAR();
    // P5
    ldA(u, 0); ldB(u, 0); if (i < 3) stage(0, 0, t + 2);
    BAR(); LGKM0(); mm(0, 0); BAR();
    // P6
    ldB(u, 2); if (i < 3) stage(0, 1, t + 2);
    BAR(); LGKM0(); mm(0, 2); BAR();
    // P7
    ldA(u, 4); if (i < 3) stage(1, 0, t + 3);
    BAR(); LGKM0(); mm(4, 0); BAR();
    // P8  (confirm tile t+2 landed before next-iter P1)
    if (i < 3) stage(1, 1, t + 3);
    BAR(); LGKM0(); mm(4, 2);
    if (i < 3) { VMCNT(4); }
    BAR(); SBAR();
  }

  // ---- epilogue: per-wave [16][68] f32 strip, 256B-contiguous nt stores
  float* S = (float*)(smem + (wid << 13));  // 8KB stride, uses 4352B
  const int crow0 = row0 + (wm << 7);
  const int ccol0 = col0 + (wn << 6);
#pragma unroll
  for (int fm = 0; fm < 8; ++fm) {
#pragma unroll
    for (int fn = 0; fn < 4; ++fn)
#pragma unroll
      for (int q = 0; q < 4; ++q)
        S[(hq * 4 + q) * 68 + fn * 16 + lr16] = acc[fm][fn][q];
#pragma unroll
    for (int j = 0; j < 4; ++j) {
      f32x4 v = *(const f32x4*)&S[(j * 4 + hq) * 68 + lr16 * 4];
      __builtin_nontemporal_store(
          v, (f32x4*)&C[(size_t)(crow0 + fm * 16 + j * 4 + hq) * N_DIM +
                        ccol0 + lr16 * 4]);
    }
  }
}

extern "C" void kernel_launch(void* const* d_in, const int* in_sizes, int n_in,
                              void* d_out, int out_size, void* d_ws, size_t ws_size,
                              hipStream_t stream) {
  const float* x = (const float*)d_in[0];
  const float* y = (const float*)d_in[1];
  float* out = (float*)d_out;
  unsigned short* xn = (unsigned short*)d_ws;                    // 8 MB
  unsigned short* yn = xn + (size_t)M_DIM * K_DIM;               // 8 MB

  // 128KB dynamic LDS needs the attribute (static cap is 64KB). Host-side,
  // not a stream op -> graph-capture safe; idempotent.
  (void)hipFuncSetAttribute((const void*)cosgemm,
                            hipFuncAttributeMaxDynamicSharedMemorySize, 131072);

  normalize_rows<<<M_DIM / 4, 256, 0, stream>>>(x, xn);
  normalize_rows<<<N_DIM / 4, 256, 0, stream>>>(y, yn);
  cosgemm<<<(M_DIM / 256) * (N_DIM / 256), 512, 131072, stream>>>(xn, yn, out);
}